// Round 2
// 12297.208 us; speedup vs baseline: 1.5520x; 1.5520x over previous
//
#include <hip/hip_runtime.h>
#include <cmath>

constexpr int B = 256, T = 1024, D = 128, H = 256, NC = 10;
constexpr int K    = D + H;        // 384 rows: [x(128) | h(256)]
constexpr int NCOL = 4 * H;        // 1024 cols: [g|i|f|o]
constexpr int KH   = K / 2;        // 192 rows per k-half
constexpr int BPB  = 3;            // batches per block
constexpr int NBLK = (B + BPB - 1) / BPB;   // 86

// ws layout (floats):
//   W  [K][NCOL]  @ 0        (1.5 MB, repacked weights)
//   hT [H][B]     @ HT_OFF   (final h, j-major for projection)
constexpr size_t W_OFF  = 0;
constexpr size_t HT_OFF = (size_t)K * NCOL;            // 393216
// total used: 458752 floats (1.75 MB).
// NOTE: weight prefetch wrap over-reads up to row K+8 -> float idx < 412000,
// still inside the used region. Safe.

__device__ __forceinline__ float fast_sig(float x) { return 1.f / (1.f + __expf(-x)); }
__device__ __forceinline__ float fast_tanh(float x) {
  float ax = fabsf(x);
  float e = __expf(2.f * ax);            // overflow -> inf -> r -> 1, safe
  float r = 1.f - 2.f / (e + 1.f);
  return copysignf(r, x);
}

// Repack weights: W[k][j], k<D from w*x, else w*h; col j: gate j>>8, unit j&255.
__global__ void setup_kernel(const float* __restrict__ wgx, const float* __restrict__ wgh,
                             const float* __restrict__ wix, const float* __restrict__ wih,
                             const float* __restrict__ wfx, const float* __restrict__ wfh,
                             const float* __restrict__ wox, const float* __restrict__ woh,
                             float* __restrict__ ws) {
  int idx = blockIdx.x * blockDim.x + threadIdx.x;     // 0 .. K*NCOL-1
  int j = idx & (NCOL - 1);
  int k = idx >> 10;
  int g = j >> 8, jj = j & (H - 1);
  const float* wxs[4] = {wgx, wix, wfx, wox};
  const float* whs[4] = {wgh, wih, wfh, woh};
  float v = (k < D) ? wxs[g][k * H + jj] : whs[g][(k - D) * H + jj];
  ws[W_OFF + idx] = v;
}

// NOTE: macro parameter must NOT be named w/x/y/z — member tokens .x/.y/.z/.w
// inside the body would be substituted by the preprocessor.
#define FMA12(row, WV) { \
  const float4 av = *(const float4*)&A[row][0]; \
  const float4 wv4 = (WV); \
  a0[0]=fmaf(av.x,wv4.x,a0[0]); a0[1]=fmaf(av.x,wv4.y,a0[1]); \
  a0[2]=fmaf(av.x,wv4.z,a0[2]); a0[3]=fmaf(av.x,wv4.w,a0[3]); \
  a1[0]=fmaf(av.y,wv4.x,a1[0]); a1[1]=fmaf(av.y,wv4.y,a1[1]); \
  a1[2]=fmaf(av.y,wv4.z,a1[2]); a1[3]=fmaf(av.y,wv4.w,a1[3]); \
  a2[0]=fmaf(av.z,wv4.x,a2[0]); a2[1]=fmaf(av.z,wv4.y,a2[1]); \
  a2[2]=fmaf(av.z,wv4.z,a2[2]); a2[3]=fmaf(av.z,wv4.w,a2[3]); }

// Persistent LSTM: each block owns BPB batch elements for all T steps.
// 512 threads = 8 waves = 2 k-halves x 4 col-blocks of 256 cols.
// Thread (half, wc, lane): 4 cols x BPB batches over 192 k-rows.
// h lives in LDS (A rows 128..383); c lives in epilogue-thread registers.
__launch_bounds__(512)
__global__ void lstm_persist(const float* __restrict__ x,
                             const float* __restrict__ bgp, const float* __restrict__ bip,
                             const float* __restrict__ bfp, const float* __restrict__ bop,
                             float* __restrict__ ws) {
  __shared__ float A[K][4];          // 6 KB: [k][batch-slot]; rows<128 = x_t, >=128 = h
  __shared__ float Z[2][NCOL][4];    // 32 KB: k-half partials

  const float* Wt = ws + W_OFF;
  float*       hT = ws + HT_OFF;

  const int tid  = threadIdx.x;
  const int lane = tid & 63;
  const int wv   = tid >> 6;
  const int half = wv >> 2;                  // k-split: 0 or 1
  const int wc   = wv & 3;                   // col-block (== gate)
  const int c0   = wc * 256 + lane * 4;
  const int k0   = half * KH;

  // epilogue role: tid<256 -> (j=tid, b=0,1); tid>=256 -> (j=tid-256, b=2)
  const int ej = tid & 255;
  const int er = tid >> 8;
  const int bfirst = er ? 2 : 0;
  const float bgv = bgp[ej], biv = bip[ej], bfv = bfp[ej], bov = bop[ej];
  float cs0 = 0.f, cs1 = 0.f, h0 = 0.f, h1 = 0.f;

  // x-stage role: thread (xb, xd) loads x[b=blk*BPB+xb][t][xd]
  const int xd = tid & 127, xb = tid >> 7;   // xb 0..3 (3 unused)
  const int bgl = blockIdx.x * BPB + xb;
  const float* xptr = x + (size_t)(bgl < B ? bgl : B - 1) * T * D + xd;

  // prologue: h_0 = 0, stage x_0
  for (int i = tid; i < H * 4; i += 512) (&A[D][0])[i] = 0.f;
  if (xb < BPB) A[xd][xb] = xptr[0];

  const float* wrow = Wt + (size_t)k0 * NCOL + c0;

  // weight reg double-buffer; wa preloaded once, wrap-reloaded across steps
  float4 wa[8], wb[8];
  #pragma unroll
  for (int u = 0; u < 8; ++u) wa[u] = *(const float4*)(wrow + (size_t)u * NCOL);

  for (int t = 0; t < T; ++t) {
    __syncthreads();   // A (x_t, h_{t-1}) staged; prev Z-reads done

    // prefetch next step's x into a register (hidden under the k-loop)
    const int tn = (t + 1 < T) ? t + 1 : t;
    float xpre = 0.f;
    if (xb < BPB) xpre = xptr[(size_t)tn * D];

    float a0[4] = {0.f,0.f,0.f,0.f}, a1[4] = {0.f,0.f,0.f,0.f}, a2[4] = {0.f,0.f,0.f,0.f};

    for (int kg = 0; kg < KH; kg += 16) {
      #pragma unroll
      for (int u = 0; u < 8; ++u)
        wb[u] = *(const float4*)(wrow + (size_t)(kg + 8 + u) * NCOL);
      #pragma unroll
      for (int u = 0; u < 8; ++u) FMA12(k0 + kg + u, wa[u]);
      {
        int kn = kg + 16; if (kn == KH) kn = 0;      // wrap: prefetch next step's first group
        #pragma unroll
        for (int u = 0; u < 8; ++u)
          wa[u] = *(const float4*)(wrow + (size_t)(kn + u) * NCOL);
      }
      #pragma unroll
      for (int u = 0; u < 8; ++u) FMA12(k0 + kg + 8 + u, wb[u]);
    }

    // k-half partials -> Z
    #pragma unroll
    for (int cc = 0; cc < 4; ++cc)
      *(float4*)&Z[half][c0 + cc][0] = make_float4(a0[cc], a1[cc], a2[cc], 0.f);

    __syncthreads();   // Z complete

    // epilogue: gates, c (regs), h -> LDS for next step
    {
      float zg = Z[0][     ej][bfirst] + Z[1][     ej][bfirst] + bgv;
      float zi = Z[0][H  + ej][bfirst] + Z[1][H  + ej][bfirst] + biv;
      float zf = Z[0][2*H+ ej][bfirst] + Z[1][2*H+ ej][bfirst] + bfv;
      float zo = Z[0][3*H+ ej][bfirst] + Z[1][3*H+ ej][bfirst] + bov;
      float gv = fast_tanh(zg), iv = fast_sig(zi), fv = fast_sig(zf), ov = fast_sig(zo);
      cs0 = gv * iv + cs0 * fv;
      h0  = fast_tanh(cs0) * ov;
      A[D + ej][bfirst] = h0;
      if (er == 0) {
        float zg1 = Z[0][     ej][1] + Z[1][     ej][1] + bgv;
        float zi1 = Z[0][H  + ej][1] + Z[1][H  + ej][1] + biv;
        float zf1 = Z[0][2*H+ ej][1] + Z[1][2*H+ ej][1] + bfv;
        float zo1 = Z[0][3*H+ ej][1] + Z[1][3*H+ ej][1] + bov;
        float gv1 = fast_tanh(zg1), iv1 = fast_sig(zi1), fv1 = fast_sig(zf1), ov1 = fast_sig(zo1);
        cs1 = gv1 * iv1 + cs1 * fv1;
        h1  = fast_tanh(cs1) * ov1;
        A[D + ej][1] = h1;
      }
    }
    // stage x_{t+1}
    if (xb < BPB) A[xd][xb] = xpre;
  }

  // final h -> ws (j-major for projection)
  {
    int b0g = blockIdx.x * BPB + bfirst;
    if (b0g < B) hT[(size_t)ej * B + b0g] = h0;
    if (er == 0) {
      int b1g = blockIdx.x * BPB + 1;
      if (b1g < B) hT[(size_t)ej * B + b1g] = h1;
    }
  }
}

// out[b][c] = sum_j hT[j][b] * wph[j][c] + bp[c]
__global__ void proj_kernel(const float* __restrict__ hTp, const float* __restrict__ wph,
                            const float* __restrict__ bp, float* __restrict__ out) {
  int b = blockIdx.x;
  int j = threadIdx.x;
  float hv = hTp[(size_t)j * B + b];
  float p[NC];
  #pragma unroll
  for (int c = 0; c < NC; ++c) p[c] = hv * wph[j * NC + c];
  #pragma unroll
  for (int off = 32; off >= 1; off >>= 1)
    #pragma unroll
    for (int c = 0; c < NC; ++c) p[c] += __shfl_xor(p[c], off, 64);
  __shared__ float s[NC];
  if (threadIdx.x < NC) s[threadIdx.x] = 0.f;
  __syncthreads();
  if ((threadIdx.x & 63) == 0)
    for (int c = 0; c < NC; ++c) atomicAdd(&s[c], p[c]);
  __syncthreads();
  if (j < NC) out[b * NC + j] = s[j] + bp[j];
}

extern "C" void kernel_launch(void* const* d_in, const int* in_sizes, int n_in,
                              void* d_out, int out_size, void* d_ws, size_t ws_size,
                              hipStream_t stream) {
  const float* x   = (const float*)d_in[0];
  const float* wgx = (const float*)d_in[1];
  const float* wgh = (const float*)d_in[2];
  const float* bg  = (const float*)d_in[3];
  const float* wix = (const float*)d_in[4];
  const float* wih = (const float*)d_in[5];
  const float* bi  = (const float*)d_in[6];
  const float* wfx = (const float*)d_in[7];
  const float* wfh = (const float*)d_in[8];
  const float* bf  = (const float*)d_in[9];
  const float* wox = (const float*)d_in[10];
  const float* woh = (const float*)d_in[11];
  const float* bo  = (const float*)d_in[12];
  const float* wph = (const float*)d_in[13];
  const float* bp  = (const float*)d_in[14];
  float* out = (float*)d_out;
  float* ws  = (float*)d_ws;

  setup_kernel<<<(K * NCOL) / 256, 256, 0, stream>>>(wgx, wgh, wix, wih,
                                                     wfx, wfh, wox, woh, ws);
  lstm_persist<<<NBLK, 512, 0, stream>>>(x, bg, bi, bf, bo, ws);
  proj_kernel<<<B, H, 0, stream>>>(ws + HT_OFF, wph, bp, out);
}